// Round 3
// baseline (233.245 us; speedup 1.0000x reference)
//
#include <hip/hip_runtime.h>
#include <math.h>

// HR_HLIFLayer2D: leaky integrate-and-fire over T=32 timesteps.
// x: (B=16, T=32, C=64, H=32, W=32) f32; vth_raw/decay_raw: (C,H,W) f32.
// out: spikes (B,T,C,H,W) f32 in {0.0, 1.0}.
//
// R3: float2/thread, 2048 blocks (32 waves/CU), depth-4 rotating prefetch
// (3 loads in flight per wave ≈ 48 KB/CU outstanding — covers ~1000-cyc HBM
// latency at 10 B/cyc/CU with margin), non-temporal spike stores.
//
// Numerics: recurrence uses explicit __fmul_rn/__fadd_rn/__fsub_rn to match
// the fp32 reference op order exactly (no FMA contraction). Params computed
// with double transcendentals, rounded once to fp32 per reference op sequence.

#define LIF_B    16
#define LIF_T    32
#define LIF_CHW  65536   // 64*32*32
#define LIF_CHW2 32768   // CHW / 2

typedef float vf2 __attribute__((ext_vector_type(2)));

__global__ __launch_bounds__(256) void HR_HLIFLayer2D_kernel(
    const float* __restrict__ x,
    const float* __restrict__ vth_raw,
    const float* __restrict__ decay_raw,
    float* __restrict__ out)
{
    const int g = blockIdx.x * 256 + threadIdx.x;   // [0, B*CHW2)
    const int b = g >> 15;                          // g / CHW2
    const int j = g & (LIF_CHW2 - 1);               // float2 index within CHW

    const vf2 vr2 = reinterpret_cast<const vf2*>(vth_raw)[j];
    const vf2 dr2 = reinterpret_cast<const vf2*>(decay_raw)[j];
    const float vrr[2] = {vr2.x, vr2.y};
    const float drr[2] = {dr2.x, dr2.y};

    float vth[2], dec[2];
#pragma unroll
    for (int i = 0; i < 2; ++i) {
        // vth = softplus(vth_raw*0.1 + 0.5) + 0.01, fp32 rounding sequence
        float a  = __fmul_rn(vrr[i], 0.1f);
        float bb = __fadd_rn(a, 0.5f);
        double sp = log1p(exp((double)bb));          // correctly-rounded softplus
        vth[i] = __fadd_rn((float)sp, 0.01f);

        // decay = clip(sigmoid(decay_raw*0.1 + 2.0), 0, 0.99)
        float z = __fmul_rn(drr[i], 0.1f);
        float w = __fadd_rn(z, 2.0f);
        double sg = 1.0 / (1.0 + exp(-(double)w));
        float sgf = (float)sg;
        sgf = fminf(fmaxf(sgf, 0.0f), 0.99f);        // never binds in practice
        dec[i] = sgf;
    }

    float v[2] = {0.f, 0.f};
    const size_t base2 = (size_t)b * (LIF_T * LIF_CHW2) + (size_t)j;
    const vf2* __restrict__ x2 = reinterpret_cast<const vf2*>(x);
    vf2* __restrict__ o2 = reinterpret_cast<vf2*>(out);

    // depth-4 rotating prefetch: issue loads for t, t+1, t+2 up front; inside
    // the (fully unrolled) loop issue t+3 before consuming t. Steady state:
    // 3 loads outstanding per wave.
    vf2 pf[4];
    pf[0] = x2[base2];
    pf[1] = x2[base2 + LIF_CHW2];
    pf[2] = x2[base2 + 2 * (size_t)LIF_CHW2];

#pragma unroll
    for (int t = 0; t < LIF_T; ++t) {
        if (t + 3 < LIF_T)                            // compile-time (full unroll)
            pf[(t + 3) & 3] = x2[base2 + (size_t)(t + 3) * LIF_CHW2];

        const vf2 xt = pf[t & 3];
        const float xi[2] = {xt.x, xt.y};
        vf2 s;
        float so[2];
#pragma unroll
        for (int i = 0; i < 2; ++i) {
            // v = v*decay + x_t   (separate mul, add — match ref rounding)
            float vv = __fadd_rn(__fmul_rn(v[i], dec[i]), xi[i]);
            // s = (v - vth > 0) ? 1 : 0
            float d = __fsub_rn(vv, vth[i]);
            bool fire = (d > 0.0f);
            so[i] = fire ? 1.0f : 0.0f;
            // v = v - s*vth: s=1 -> exactly d (fl(v - vth)); s=0 -> exactly vv
            v[i] = fire ? d : vv;
        }
        s.x = so[0]; s.y = so[1];
        __builtin_nontemporal_store(s, &o2[base2 + (size_t)t * LIF_CHW2]);
    }
}

extern "C" void kernel_launch(void* const* d_in, const int* in_sizes, int n_in,
                              void* d_out, int out_size, void* d_ws, size_t ws_size,
                              hipStream_t stream) {
    const float* x         = (const float*)d_in[0];
    const float* vth_raw   = (const float*)d_in[1];
    const float* decay_raw = (const float*)d_in[2];
    float* out             = (float*)d_out;

    const int total_threads = LIF_B * LIF_CHW2;   // 524288
    const int block = 256;
    const int grid = total_threads / block;       // 2048 blocks = 8 blocks/CU
    HR_HLIFLayer2D_kernel<<<grid, block, 0, stream>>>(x, vth_raw, decay_raw, out);
}